// Round 5
// baseline (235.885 us; speedup 1.0000x reference)
//
#include <hip/hip_runtime.h>

// RetrievalHeadPyramidBottomUpInstantSimple
// feat0 [32,256,56,56], feat1 [32,512,28,28], feat2 [32,1024,14,14],
// feat3 [32,2048,7,7], conv_w [1024,3840]  (all fp32) -> out [32,1024] fp32
//
// Identity: jax bilinear half-pixel upsample by integer factor to 56x56 has
// exactly-uniform per-input-pixel weight column sums, so
// mean(upsample(f)) == mean(f).  Hence:
//   out = concat_l(spatial_mean(feat_l)) @ conv_w^T
//
// R4 post-mortem: three different pool structures all pinned at 1.2-1.4 TB/s;
// common factor = per-block vmcnt(0) drain bubbles. R5: persistent pipelined
// pool — 1536 blocks x 10 chunks, double-buffered LDS, vmcnt(4) (never 0
// until tail), per-wave self-contained slices (no cross-wave LDS deps).

#define AS1(p) ((const __attribute__((address_space(1))) void*)(p))
#define AS3(p) ((__attribute__((address_space(3))) void*)(p))

__global__ __launch_bounds__(256) void pool_kernel(
    const float* __restrict__ f0, const float* __restrict__ f1,
    const float* __restrict__ f2, const float* __restrict__ f3,
    float* __restrict__ v)
{
    __shared__ float l[2 * 3136 + 8];   // double buffer + f0 combine slots
    int t = threadIdx.x, w = t >> 6, lane = t & 63;
    float* warr = l + 6272;

    // chunk c (0..15359) -> 3136 contiguous floats of one level
    // f0: c in [0,8192)  f1: [8192,12288)  f2: [12288,14336)  f3: [14336,15360)
    int c0 = blockIdx.x;                // this block: chunks c0 + 1536*i

    // ---- stage chunk c's own wave-slice (784 floats) into buf ----
    auto stage = [&](int c, int buf) {
        const float* base;
        if (c < 8192)       base = f0 + (size_t)c * 3136;
        else if (c < 12288) base = f1 + (size_t)(c - 8192) * 3136;
        else if (c < 14336) base = f2 + (size_t)(c - 12288) * 3136;
        else                base = f3 + (size_t)(c - 14336) * 3136;
        const float* g = base + w * 784;
        float* ld = l + buf * 3136 + w * 784;
        #pragma unroll
        for (int r = 0; r < 3; ++r)
            __builtin_amdgcn_global_load_lds(
                AS1(g + r * 256 + lane * 4), AS3(ld + r * 256), 16, 0, 0);
        if (lane < 4)
            __builtin_amdgcn_global_load_lds(
                AS1(g + 768 + lane * 4), AS3(ld + 768), 16, 0, 0);
    };

    stage(c0, 0);
    #pragma unroll 1
    for (int i = 0; i < 10; ++i) {
        int c = c0 + 1536 * i;
        if (i < 9) {
            stage(c0 + 1536 * (i + 1), (i + 1) & 1);
            asm volatile("s_waitcnt vmcnt(4)" ::: "memory");
        } else {
            asm volatile("s_waitcnt vmcnt(0)" ::: "memory");
        }

        // sum own 784-float slice: 16 segs of 49; lane = (seg<<2)|part
        const float* ldb = l + (i & 1) * 3136 + w * 784;
        const float* seg = ldb + (lane >> 2) * 49 + (lane & 3) * 12;
        float s = 0.f;
        #pragma unroll
        for (int k = 0; k < 12; ++k) s += seg[k];
        if ((lane & 3) == 3) s += seg[12];
        s += __shfl_xor(s, 1); s += __shfl_xor(s, 2);   // seg sums

        if (c < 8192) {
            // plane = whole block chunk (3136)
            s += __shfl_xor(s, 4);  s += __shfl_xor(s, 8);
            s += __shfl_xor(s, 16); s += __shfl_xor(s, 32);
            if (lane == 0) warr[(i & 1) * 4 + w] = s;
            __syncthreads();
            if (t == 0) {
                const float* wa = warr + (i & 1) * 4;
                v[(c >> 8) * 3840 + (c & 255)] =
                    (wa[0] + wa[1] + wa[2] + wa[3]) * (1.f / 3136.f);
            }
        } else if (c < 12288) {
            // plane = wave slice (784)
            s += __shfl_xor(s, 4);  s += __shfl_xor(s, 8);
            s += __shfl_xor(s, 16); s += __shfl_xor(s, 32);
            if (lane == 0) {
                int q = (c - 8192) * 4 + w;
                v[(q >> 9) * 3840 + 256 + (q & 511)] = s * (1.f / 784.f);
            }
        } else if (c < 14336) {
            // plane = 4 segs (196)
            s += __shfl_xor(s, 4); s += __shfl_xor(s, 8);
            if ((lane & 15) == 0) {
                int q = (c - 12288) * 16 + w * 4 + (lane >> 4);
                v[(q >> 10) * 3840 + 768 + (q & 1023)] = s * (1.f / 196.f);
            }
        } else {
            // plane = seg (49)
            if ((lane & 3) == 0) {
                int q = (c - 14336) * 64 + w * 16 + (lane >> 2);
                v[(q >> 11) * 3840 + 1792 + (q & 2047)] = s * (1.f / 49.f);
            }
        }
    }
}

// GEMM: out[b,e] = sum_k v[b,k]*W[e,k]; M=32,N=1024,K=3840
// e-tile 64, split-K x32 (KT=120) -> grid 512 blocks.
#define KT 120

__global__ __launch_bounds__(256) void gemm_kernel(
    const float* __restrict__ v, const float* __restrict__ W,
    float* __restrict__ partials)
{
    __shared__ float vs[32][124];
    __shared__ float wsh[64][124];
    int t = threadIdx.x;
    int et = blockIdx.x & 15, ks = blockIdx.x >> 4;
    int e0 = et << 6, k0 = ks * KT;

    // stage W tile: 64 rows x 30 f4 = 1920 f4 — batch loads, then writes
    {
        float4 tmp[7];
        int row[7], c4[7];
        #pragma unroll
        for (int i = 0; i < 7; ++i) {
            int f = t + (i << 8);
            row[i] = f / 30; c4[i] = f % 30;
            tmp[i] = *(const float4*)&W[(size_t)(e0 + row[i]) * 3840 + k0 + c4[i] * 4];
        }
        float4 tail; int rowt = 0, c4t = 0;
        if (t < 128) {
            int f = t + 1792;
            rowt = f / 30; c4t = f % 30;
            tail = *(const float4*)&W[(size_t)(e0 + rowt) * 3840 + k0 + c4t * 4];
        }
        #pragma unroll
        for (int i = 0; i < 7; ++i)
            *(float4*)&wsh[row[i]][c4[i] * 4] = tmp[i];
        if (t < 128)
            *(float4*)&wsh[rowt][c4t * 4] = tail;
    }
    // stage v tile: 32 rows x 30 f4 = 960 f4
    {
        float4 tmp[3];
        int row[3], c4[3];
        #pragma unroll
        for (int i = 0; i < 3; ++i) {
            int f = t + (i << 8);
            row[i] = f / 30; c4[i] = f % 30;
            tmp[i] = *(const float4*)&v[row[i] * 3840 + k0 + c4[i] * 4];
        }
        float4 tail; int rowt = 0, c4t = 0;
        if (t < 192) {
            int f = t + 768;
            rowt = f / 30; c4t = f % 30;
            tail = *(const float4*)&v[rowt * 3840 + k0 + c4t * 4];
        }
        #pragma unroll
        for (int i = 0; i < 3; ++i)
            *(float4*)&vs[row[i]][c4[i] * 4] = tmp[i];
        if (t < 192)
            *(float4*)&vs[rowt][c4t * 4] = tail;
    }
    __syncthreads();

    int bg = t >> 5, eg = t & 31;
    int b0 = bg << 2;
    float acc[4][2] = {};
    #pragma unroll 5
    for (int k = 0; k < KT; k += 4) {
        float4 vv[4], ww[2];
        #pragma unroll
        for (int i = 0; i < 4; ++i) vv[i] = *(const float4*)&vs[b0 + i][k];
        #pragma unroll
        for (int j = 0; j < 2; ++j) ww[j] = *(const float4*)&wsh[eg + (j << 5)][k];
        #pragma unroll
        for (int i = 0; i < 4; ++i)
            #pragma unroll
            for (int j = 0; j < 2; ++j)
                acc[i][j] += vv[i].x * ww[j].x + vv[i].y * ww[j].y +
                             vv[i].z * ww[j].z + vv[i].w * ww[j].w;
    }

    float* pout = partials + (size_t)ks * 32768 + (size_t)b0 * 1024 + e0 + eg;
    #pragma unroll
    for (int i = 0; i < 4; ++i)
        #pragma unroll
        for (int j = 0; j < 2; ++j)
            pout[i * 1024 + (j << 5)] = acc[i][j];
}

__global__ __launch_bounds__(256) void reduce_kernel(
    const float* __restrict__ partials, float* __restrict__ out)
{
    int idx = blockIdx.x * 256 + threadIdx.x;  // 0..32767
    float s0 = 0.f, s1 = 0.f, s2 = 0.f, s3 = 0.f;
    #pragma unroll
    for (int sp = 0; sp < 32; sp += 4) {
        s0 += partials[(sp + 0) * 32768 + idx];
        s1 += partials[(sp + 1) * 32768 + idx];
        s2 += partials[(sp + 2) * 32768 + idx];
        s3 += partials[(sp + 3) * 32768 + idx];
    }
    out[idx] = (s0 + s1) + (s2 + s3);
}

extern "C" void kernel_launch(void* const* d_in, const int* in_sizes, int n_in,
                              void* d_out, int out_size, void* d_ws, size_t ws_size,
                              hipStream_t stream)
{
    const float* f0 = (const float*)d_in[0];
    const float* f1 = (const float*)d_in[1];
    const float* f2 = (const float*)d_in[2];
    const float* f3 = (const float*)d_in[3];
    const float* W  = (const float*)d_in[4];
    float* out = (float*)d_out;

    float* v        = (float*)d_ws;      // 32*3840 floats
    float* partials = v + 32 * 3840;     // 32*32768 floats = 4 MB

    pool_kernel<<<1536, 256, 0, stream>>>(f0, f1, f2, f3, v);
    gemm_kernel<<<512, 256, 0, stream>>>(v, W, partials);
    reduce_kernel<<<128, 256, 0, stream>>>(partials, out);
}

// Round 6
// 233.376 us; speedup vs baseline: 1.0108x; 1.0108x over previous
//
#include <hip/hip_runtime.h>

// RetrievalHeadPyramidBottomUpInstantSimple
// feat0 [32,256,56,56], feat1 [32,512,28,28], feat2 [32,1024,14,14],
// feat3 [32,2048,7,7], conv_w [1024,3840]  (all fp32) -> out [32,1024] fp32
//
// Identity: jax bilinear half-pixel upsample by integer factor to 56x56 has
// exactly-uniform per-input-pixel weight column sums, so
// mean(upsample(f)) == mean(f).  Hence:
//   out = concat_l(spatial_mean(feat_l)) @ conv_w^T
//
// R5 post-mortem: 4 pool structures pinned at ~1.35 TB/s HBM / 2.75 TB/s
// effective. R6 discriminator: m13-style pool — pure register float4 loads,
// zero LDS, zero barriers, plane sums via lane predication + shuffles.

__device__ __forceinline__ float s4(float4 a) { return (a.x + a.y) + (a.z + a.w); }

__global__ __launch_bounds__(256) void pool_kernel(
    const float* __restrict__ f0, const float* __restrict__ f1,
    const float* __restrict__ f2, const float* __restrict__ f3,
    float* __restrict__ v)
{
    int t = threadIdx.x, w = t >> 6, lane = t & 63;
    int bid = blockIdx.x;

    if (bid < 3072) {
        // ---- f0/f1: one wave per 3136-float chunk, 12+1 float4 regs ----
        int chunk = bid * 4 + w;            // [0,12288)
        const float* base = (chunk < 8192)
            ? f0 + (size_t)chunk * 3136
            : f1 + (size_t)(chunk - 8192) * 3136;
        const float4* p = (const float4*)base;
        float4 r[12];
        #pragma unroll
        for (int i = 0; i < 12; ++i) r[i] = p[lane + (i << 6)];
        float4 tl = make_float4(0.f, 0.f, 0.f, 0.f);
        if (lane < 16) tl = p[768 + lane];

        if (chunk < 8192) {
            // one chunk == one f0 plane
            float s = 0.f;
            #pragma unroll
            for (int i = 0; i < 12; ++i) s += s4(r[i]);
            s += s4(tl);
            #pragma unroll
            for (int o = 32; o; o >>= 1) s += __shfl_xor(s, o);
            if (lane == 0)
                v[(chunk >> 8) * 3840 + (chunk & 255)] = s * (1.f / 3136.f);
        } else {
            // one chunk == 4 f1 planes (784 floats = 196 f4 each)
            // round r covers f4 [64r,64r+64); plane = f4/196
            float a0 = s4(r[0]) + s4(r[1]) + s4(r[2]) + (lane <  4 ? s4(r[3]) : 0.f);
            float a1 = (lane <  4 ? 0.f : s4(r[3])) + s4(r[4]) + s4(r[5])
                     + (lane <  8 ? s4(r[6]) : 0.f);
            float a2 = (lane <  8 ? 0.f : s4(r[6])) + s4(r[7]) + s4(r[8])
                     + (lane < 12 ? s4(r[9]) : 0.f);
            float a3 = (lane < 12 ? 0.f : s4(r[9])) + s4(r[10]) + s4(r[11]) + s4(tl);
            #pragma unroll
            for (int o = 32; o; o >>= 1) {
                a0 += __shfl_xor(a0, o); a1 += __shfl_xor(a1, o);
                a2 += __shfl_xor(a2, o); a3 += __shfl_xor(a3, o);
            }
            if (lane == 0) {
                int q = (chunk - 8192) * 4;          // first f1 plane id
                float4 res = make_float4(a0, a1, a2, a3);
                *(float4*)&v[(q >> 9) * 3840 + 256 + (q & 511)] =
                    make_float4(res.x * (1.f / 784.f), res.y * (1.f / 784.f),
                                res.z * (1.f / 784.f), res.w * (1.f / 784.f));
            }
        }
    } else {
        // ---- f2/f3: one thread per 49-float segment ----
        int seg = (bid - 3072) * 256 + t;   // [0,196608)
        const float* sp = (seg < 131072)
            ? f2 + (size_t)seg * 49
            : f3 + (size_t)(seg - 131072) * 49;
        float x[49];
        #pragma unroll
        for (int i = 0; i < 49; ++i) x[i] = sp[i];
        float s = 0.f;
        #pragma unroll
        for (int i = 0; i < 48; i += 2) s += x[i] + x[i + 1];
        s += x[48];
        if (seg < 131072) {
            // f2 plane = 4 consecutive segs (adjacent lanes)
            s += __shfl_xor(s, 1); s += __shfl_xor(s, 2);
            if ((lane & 3) == 0) {
                int q = seg >> 2;
                v[(q >> 10) * 3840 + 768 + (q & 1023)] = s * (1.f / 196.f);
            }
        } else {
            int q = seg - 131072;           // f3 plane == seg
            v[(q >> 11) * 3840 + 1792 + (q & 2047)] = s * (1.f / 49.f);
        }
    }
}

// GEMM: out[b,e] = sum_k v[b,k]*W[e,k]; M=32,N=1024,K=3840
// e-tile 64, split-K x32 (KT=120) -> grid 512 blocks.
#define KT 120

__global__ __launch_bounds__(256) void gemm_kernel(
    const float* __restrict__ v, const float* __restrict__ W,
    float* __restrict__ partials)
{
    __shared__ float vs[32][124];
    __shared__ float wsh[64][124];
    int t = threadIdx.x;
    int et = blockIdx.x & 15, ks = blockIdx.x >> 4;
    int e0 = et << 6, k0 = ks * KT;

    // stage W tile: 64 rows x 30 f4 = 1920 f4 — batch loads, then writes
    {
        float4 tmp[7];
        int row[7], c4[7];
        #pragma unroll
        for (int i = 0; i < 7; ++i) {
            int f = t + (i << 8);
            row[i] = f / 30; c4[i] = f % 30;
            tmp[i] = *(const float4*)&W[(size_t)(e0 + row[i]) * 3840 + k0 + c4[i] * 4];
        }
        float4 tail; int rowt = 0, c4t = 0;
        if (t < 128) {
            int f = t + 1792;
            rowt = f / 30; c4t = f % 30;
            tail = *(const float4*)&W[(size_t)(e0 + rowt) * 3840 + k0 + c4t * 4];
        }
        #pragma unroll
        for (int i = 0; i < 7; ++i)
            *(float4*)&wsh[row[i]][c4[i] * 4] = tmp[i];
        if (t < 128)
            *(float4*)&wsh[rowt][c4t * 4] = tail;
    }
    // stage v tile: 32 rows x 30 f4 = 960 f4
    {
        float4 tmp[3];
        int row[3], c4[3];
        #pragma unroll
        for (int i = 0; i < 3; ++i) {
            int f = t + (i << 8);
            row[i] = f / 30; c4[i] = f % 30;
            tmp[i] = *(const float4*)&v[row[i] * 3840 + k0 + c4[i] * 4];
        }
        float4 tail; int rowt = 0, c4t = 0;
        if (t < 192) {
            int f = t + 768;
            rowt = f / 30; c4t = f % 30;
            tail = *(const float4*)&v[rowt * 3840 + k0 + c4t * 4];
        }
        #pragma unroll
        for (int i = 0; i < 3; ++i)
            *(float4*)&vs[row[i]][c4[i] * 4] = tmp[i];
        if (t < 192)
            *(float4*)&vs[rowt][c4t * 4] = tail;
    }
    __syncthreads();

    int bg = t >> 5, eg = t & 31;
    int b0 = bg << 2;
    float acc[4][2] = {};
    #pragma unroll 5
    for (int k = 0; k < KT; k += 4) {
        float4 vv[4], ww[2];
        #pragma unroll
        for (int i = 0; i < 4; ++i) vv[i] = *(const float4*)&vs[b0 + i][k];
        #pragma unroll
        for (int j = 0; j < 2; ++j) ww[j] = *(const float4*)&wsh[eg + (j << 5)][k];
        #pragma unroll
        for (int i = 0; i < 4; ++i)
            #pragma unroll
            for (int j = 0; j < 2; ++j)
                acc[i][j] += vv[i].x * ww[j].x + vv[i].y * ww[j].y +
                             vv[i].z * ww[j].z + vv[i].w * ww[j].w;
    }

    float* pout = partials + (size_t)ks * 32768 + (size_t)b0 * 1024 + e0 + eg;
    #pragma unroll
    for (int i = 0; i < 4; ++i)
        #pragma unroll
        for (int j = 0; j < 2; ++j)
            pout[i * 1024 + (j << 5)] = acc[i][j];
}

__global__ __launch_bounds__(256) void reduce_kernel(
    const float* __restrict__ partials, float* __restrict__ out)
{
    int idx = blockIdx.x * 256 + threadIdx.x;  // 0..32767
    float s0 = 0.f, s1 = 0.f, s2 = 0.f, s3 = 0.f;
    #pragma unroll
    for (int sp = 0; sp < 32; sp += 4) {
        s0 += partials[(sp + 0) * 32768 + idx];
        s1 += partials[(sp + 1) * 32768 + idx];
        s2 += partials[(sp + 2) * 32768 + idx];
        s3 += partials[(sp + 3) * 32768 + idx];
    }
    out[idx] = (s0 + s1) + (s2 + s3);
}

extern "C" void kernel_launch(void* const* d_in, const int* in_sizes, int n_in,
                              void* d_out, int out_size, void* d_ws, size_t ws_size,
                              hipStream_t stream)
{
    const float* f0 = (const float*)d_in[0];
    const float* f1 = (const float*)d_in[1];
    const float* f2 = (const float*)d_in[2];
    const float* f3 = (const float*)d_in[3];
    const float* W  = (const float*)d_in[4];
    float* out = (float*)d_out;

    float* v        = (float*)d_ws;      // 32*3840 floats
    float* partials = v + 32 * 3840;     // 32*32768 floats = 4 MB

    pool_kernel<<<3840, 256, 0, stream>>>(f0, f1, f2, f3, v);
    gemm_kernel<<<512, 256, 0, stream>>>(v, W, partials);
    reduce_kernel<<<128, 256, 0, stream>>>(partials, out);
}